// Round 12
// baseline (416.191 us; speedup 1.0000x reference)
//
#include <hip/hip_runtime.h>

#define NUM_DENSE 13
#define NUM_SPARSE 26
#define FEAT_NUM 40000
#define FEATURE_LENGTH (NUM_SPARSE * FEAT_NUM + NUM_DENSE)  // 1,040,013
#define KDIM 64
#define BATCH 4096
#define QSIZE 4000          // floats per chunk: 10 chunks per 40000-window
#define NCHUNK 10
#define LDSN (QSIZE + 4)    // 4004 floats = 16,016 B
#define NT 1024
#define NG 8                // 64 k x 8 g = 512 blocks = 2 blocks/CU
#define NBUF 4              // LDS ring
#define LA 4                // register-stage lookahead (stages in flight)

// K0: setup. 2048 blocks x 256 thr = 524,288 threads = exactly PS+PQ floats.
// Every thread zeroes one float of the PS|PQ region (needed every launch:
// harness poisons ws, and accum now accumulates atomically); the first
// 106,496 threads also transpose sparse indices to [slot][batch].
__global__ void setup_kernel(const int* __restrict__ sp, int* __restrict__ sp_t,
                             float* __restrict__ Z) {
    int gid = blockIdx.x * blockDim.x + threadIdx.x;
    Z[gid] = 0.f;
    if (gid < NUM_SPARSE * BATCH) {
        int j = gid >> 12, b = gid & 4095;
        sp_t[gid] = sp[b * NUM_SPARSE + j];
    }
}

// Opaque asm global load: invisible to the compiler's waitcnt pass -> it can
// never insert a vmcnt(0) drain for these at barriers/clobbered asm. All vmcnt
// discipline is manual. Compiler-visible vmem (idx preload, spills) only ever
// ADDS newer queue entries -> manual waits (targeting the oldest) stay safe.
__device__ __forceinline__ float4 gload16(const float4* p) {
    float4 r;
    asm volatile("global_load_dwordx4 %0, %1, off"
                 : "=&v"(r)
                 : "v"((const __attribute__((address_space(1))) float4*)p));
    return r;
}

// Plain LDS write (ds_write_b128): not vmem -> cannot cause a vmcnt drain;
// compiler auto-handles the pending-ds_write-source vs next-load VGPR hazard;
// pinned in place by the memory-clobbered asm above and below it.
__device__ __forceinline__ void swrite16(float* lp, float4 v) {
    *reinterpret_cast<float4*>(lp) = v;
}

// K1: PASS A (pure-stream probe, no barriers) + PASS B (proven reg-staged
// counted-vmcnt pipeline), stores via atomicAdd into PS[k][b]/PQ[k][b].
__global__ __launch_bounds__(NT, 8) void accum_kernel(const float* __restrict__ V,
                                                      const int* __restrict__ sp_t,
                                                      float* __restrict__ PS,
                                                      float* __restrict__ PQ) {
    __shared__ __align__(16) float buf[NBUF][LDSN];   // 4 x 16,016 B = 64 KB

    const int k = blockIdx.x;
    const int g = blockIdx.y;
    const int tid = threadIdx.x;
    const int jstart = (g * NUM_SPARSE) / NG;        // 0,3,6,9,13,16,19,22
    const int jend   = ((g + 1) * NUM_SPARSE) / NG;
    const int nw     = jend - jstart;                // 3 or 4 windows

    const size_t kbase = (size_t)k * FEATURE_LENGTH + NUM_DENSE;
    const int a   = (int)(kbase & 3);        // k=63 -> 0 (exact end, no OOB)
    const int nl4 = (QSIZE + a + 3) >> 2;    // 1000 or 1001 float4 per chunk
    const int nstage = nw * NCHUNK;

    const float4* g4b = (const float4*)(V + kbase + (size_t)jstart * FEAT_NUM - a) + tid;
    const bool ld = (tid < nl4);   // every wave keeps >=1 active lane

    // preload ALL window indices into named registers (no tracked vmem in loop)
    int s0[4], s1[4], s2[4], s3[4];
#pragma unroll
    for (int r = 0; r < 4; ++r) {
        s0[r] = sp_t[(jstart + 0) * BATCH + tid + NT * r];
        s1[r] = sp_t[(jstart + 1) * BATCH + tid + NT * r];
        s2[r] = sp_t[(jstart + 2) * BATCH + tid + NT * r];
    }
    if (nw == 4) {
#pragma unroll
        for (int r = 0; r < 4; ++r) s3[r] = sp_t[(jstart + 3) * BATCH + tid + NT * r];
    } else {
#pragma unroll
        for (int r = 0; r < 4; ++r) s3[r] = 0;
    }

    float sAcc[4] = {0.f, 0.f, 0.f, 0.f};
    float qAcc[4] = {0.f, 0.f, 0.f, 0.f};
    int cs[4];
#pragma unroll
    for (int r = 0; r < 4; ++r) cs[r] = s0[r];

    __syncthreads();   // drain idx loads: hardware vm queue empty from here

    // ---- PASS A (probe): cold pure-stream of this block's V range. Same
    // addresses and per-wave depth-4 as the pipeline, but NO barriers and NO
    // LDS. Results discarded (volatile asm is not deletable; dest regs never
    // read, so WAW garbage is benign). T_A isolates the raw HBM pattern cost.
    if (ld) {
        int t = 0;
        for (; t + 4 <= nstage; t += 4) {
            (void)gload16(g4b + (size_t)(t + 0) * 1000);
            asm volatile("s_waitcnt vmcnt(3)");
            (void)gload16(g4b + (size_t)(t + 1) * 1000);
            asm volatile("s_waitcnt vmcnt(3)");
            (void)gload16(g4b + (size_t)(t + 2) * 1000);
            asm volatile("s_waitcnt vmcnt(3)");
            (void)gload16(g4b + (size_t)(t + 3) * 1000);
            asm volatile("s_waitcnt vmcnt(3)");
        }
        for (; t < nstage; ++t) {
            (void)gload16(g4b + (size_t)t * 1000);
            asm volatile("s_waitcnt vmcnt(3)");
        }
    }
    asm volatile("s_waitcnt vmcnt(0)");   // clean queue entering PASS B

    // ---- PASS B: the R9 pipeline, byte-identical structure ----
    float4 R[4];       // statically indexed after unroll (no scratch)
    if (ld) {
        R[0] = gload16(g4b);
        R[1] = gload16(g4b + 1000);
        R[2] = gload16(g4b + 2000);
        R[3] = gload16(g4b + 3000);
    }
    asm volatile("s_waitcnt vmcnt(3)" ::: "memory");  // stage 0 resident in R[0]
    if (ld) swrite16(&buf[0][4 * tid], R[0]);

    int wg = 0, qg = 0;
    for (int sb = 0; sb < nstage; sb += 4) {
#pragma unroll
        for (int u = 0; u < 4; ++u) {
            const int s = sb + u;
            if (s < nstage) {
                // 1) issue load(s+LA) into the slot stage s vacated
                if (s + LA < nstage && ld)
                    R[u] = gload16(g4b + (size_t)(s + LA) * 1000);
                // 2) counted wait for stage s+1's load, then stage it to LDS
                if (s + 1 < nstage) {
                    const int pend = (nstage - 2 - s < 3) ? (nstage - 2 - s) : 3;
                    if (pend == 3)      asm volatile("s_waitcnt vmcnt(3)" ::: "memory");
                    else if (pend == 2) asm volatile("s_waitcnt vmcnt(2)" ::: "memory");
                    else if (pend == 1) asm volatile("s_waitcnt vmcnt(1)" ::: "memory");
                    else                asm volatile("s_waitcnt vmcnt(0)" ::: "memory");
                    if (ld) swrite16(&buf[(u + 1) & 3][4 * tid], R[(u + 1) & 3]);
                }
                // 3) writes visible + order gathers (no tracked vmem in loop
                //    -> no compiler vmcnt drain possible)
                asm volatile("s_waitcnt lgkmcnt(0)" ::: "memory");
                __builtin_amdgcn_s_barrier();
                asm volatile("" ::: "memory");

                // 4) gather stage s
                const int q0 = qg * QSIZE;
                const float* __restrict__ bb = buf[u];
#pragma unroll
                for (int r = 0; r < 4; ++r) {
                    int rel = cs[r] - q0;
                    bool in = (rel >= 0) && (rel < QSIZE);
                    int addr = in ? (rel + a) : 0;   // masked: broadcast read, free
                    float v = bb[addr];
                    v = in ? v : 0.f;
                    sAcc[r] += v;
                    qAcc[r] += v * v;
                }
                if (++qg == NCHUNK) {
                    qg = 0; ++wg;
                    if (wg < nw) {
#pragma unroll
                        for (int r = 0; r < 4; ++r)
                            cs[r] = (wg == 1) ? s1[r] : (wg == 2) ? s2[r] : s3[r];
                    }
                }
            }
        }
    }

    // atomic g-reduction into PS[k][b] (coalesced 64-lane bursts; 8 adds/cell
    // device-wide; fp32 reorder noise ~1e-5 << 5.4e-2 threshold)
    const int base = k * BATCH + tid;
#pragma unroll
    for (int r = 0; r < 4; ++r) {
        atomicAdd(&PS[base + NT * r], sAcc[r]);
        atomicAdd(&PQ[base + NT * r], qAcc[r]);
    }
}

// K2: final. 64 blocks x 256 thr; block = 64 batch rows (lane) x 4 k-groups
// (wave, 16 k each). PS/PQ reads are lane-consecutive (256 B coalesced).
__global__ __launch_bounds__(256) void final_kernel(const float* __restrict__ dense,
                                                    const float* __restrict__ w0,
                                                    const float* __restrict__ w,
                                                    const float* __restrict__ V,
                                                    const int* __restrict__ sp_t,
                                                    const float* __restrict__ PS,
                                                    const float* __restrict__ PQ,
                                                    float* __restrict__ out) {
    __shared__ float VdL[KDIM][16];    // V[:, 0:13] dense columns, padded
    __shared__ float red[4][68];
    const int tid  = threadIdx.x;
    const int lane = tid & 63;
    const int wv   = tid >> 6;                 // 0..3
    const int b    = blockIdx.x * 64 + lane;

    for (int i = tid; i < KDIM * 16; i += 256) {
        int kk = i >> 4, d = i & 15;
        if (d < NUM_DENSE) VdL[kk][d] = V[(size_t)kk * FEATURE_LENGTH + d];
    }
    __syncthreads();

    float x[NUM_DENSE], x2[NUM_DENSE];
#pragma unroll
    for (int d = 0; d < NUM_DENSE; ++d) {
        x[d]  = dense[b * NUM_DENSE + d];
        x2[d] = x[d] * x[d];
    }

    float tt = 0.f;
#pragma unroll
    for (int i = 0; i < 16; ++i) {
        const int kk = wv * 16 + i;
        float sv = PS[kk * BATCH + b];         // coalesced
        float qv = PQ[kk * BATCH + b];
#pragma unroll
        for (int d = 0; d < NUM_DENSE; ++d) {
            float vv = VdL[kk][d];             // uniform per iter -> broadcast
            sv += x[d] * vv;
            qv += x2[d] * vv * vv;
        }
        tt += sv * sv - qv;
    }
    red[wv][lane] = tt;
    __syncthreads();

    if (tid < 64) {                            // wave 0; lane's x[] matches b
        float acc = w0[0] + 0.5f * (red[0][lane] + red[1][lane] +
                                    red[2][lane] + red[3][lane]);
        int idx[NUM_SPARSE];
#pragma unroll
        for (int j = 0; j < NUM_SPARSE; ++j) idx[j] = sp_t[j * BATCH + b];
#pragma unroll
        for (int j = 0; j < NUM_SPARSE; ++j)
            acc += w[NUM_DENSE + j * FEAT_NUM + idx[j]];
#pragma unroll
        for (int d = 0; d < NUM_DENSE; ++d) acc += x[d] * w[d];
        out[b] = acc;
    }
}

extern "C" void kernel_launch(void* const* d_in, const int* in_sizes, int n_in,
                              void* d_out, int out_size, void* d_ws, size_t ws_size,
                              hipStream_t stream) {
    const float* dense  = (const float*)d_in[0];
    const int*   sparse = (const int*)d_in[1];
    const float* w0     = (const float*)d_in[2];
    const float* w      = (const float*)d_in[3];
    const float* V      = (const float*)d_in[4];
    float* out = (float*)d_out;

    char* ws = (char*)d_ws;
    int*   sp_t = (int*)ws;                         // 425,984 B
    float* PS   = (float*)(ws + (1 << 19));         // 64*4096*4 = 1 MB
    float* PQ   = (float*)(ws + (1 << 19) + (1 << 20));
    float* Z    = PS;                               // PS|PQ contiguous, 524,288 floats

    setup_kernel<<<2048, 256, 0, stream>>>(sparse, sp_t, Z);
    accum_kernel<<<dim3(KDIM, NG), NT, 0, stream>>>(V, sp_t, PS, PQ);
    final_kernel<<<BATCH / 64, 256, 0, stream>>>(dense, w0, w, V, sp_t, PS, PQ, out);
}